// Round 1
// baseline (510.453 us; speedup 1.0000x reference)
//
#include <hip/hip_runtime.h>
#include <math.h>

#define BB 64
#define SS 512
#define DD 4096
#define KK 8
#define COND_H 256
#define SIG_F 128
#define SIG_H 256
#define KD (KK*DD)        // 32768
#define SCHUNKS 8
#define SROWS (SS/SCHUNKS) // 64

// ---- seqlens dtype detection (int64 vs int32) ----
// Reference declares int64, but JAX without x64 canonicalizes to int32.
// If int64 (little-endian), the high 32-bit words (odd int32 indices) of the
// first 32 entries are all zero (values in [0,504)). Probability of false
// positive with int32 data: ~(1/504)^32 ~ 0.
__device__ inline bool seql_is64(const int* sq) {
    bool is64 = true;
#pragma unroll
    for (int i = 1; i < 64; i += 2) is64 &= (sq[i] == 0);
    return is64;
}
__device__ inline int load_seqlen(const int* sq, int b, bool is64) {
    return is64 ? sq[2 * b] : sq[b];
}

// ---------------------------------------------------------------
// Kernel 1: copy emb -> out, accumulate masked partial sums for pooling.
// grid (4 dchunks, 8 schunks, 64 b), 256 threads, float4 per thread.
// partial layout: [SCHUNKS][B][D]
// ---------------------------------------------------------------
__global__ __launch_bounds__(256) void k_copy_pool(
        const float* __restrict__ emb, const int* __restrict__ seql_raw,
        float* __restrict__ out, float* __restrict__ partial) {
    const int dchunk = blockIdx.x;   // 0..3
    const int sy     = blockIdx.y;   // 0..7
    const int b      = blockIdx.z;   // 0..63
    const int tid    = threadIdx.x;
    const int d0     = dchunk * 1024 + tid * 4;

    const bool is64 = seql_is64(seql_raw);
    const int  sl   = load_seqlen(seql_raw, b, is64);

    size_t base = ((size_t)b * SS + (size_t)sy * SROWS) * DD + d0;
    float4 sum = make_float4(0.f, 0.f, 0.f, 0.f);

    const int s0 = sy * SROWS;
#pragma unroll 4
    for (int i = 0; i < SROWS; ++i) {
        float4 v = *(const float4*)(emb + base);
        *(float4*)(out + base) = v;
        if (s0 + i < sl) {
            sum.x += v.x; sum.y += v.y; sum.z += v.z; sum.w += v.w;
        }
        base += DD;
    }
    size_t pidx = ((size_t)sy * BB + b) * DD + d0;
    *(float4*)(partial + pidx) = sum;
}

// ---------------------------------------------------------------
// Kernel 2: fused first layers.
// blocks 0..63   : cond MLP layer 1 (pooled @ W1 + b1, exact GELU) -> h_ws
// blocks 64..127 : sigma features + sW1 layer (SiLU) -> sh_ws
// ---------------------------------------------------------------
__global__ __launch_bounds__(256) void k_layer1(
        const float* __restrict__ partial, const int* __restrict__ seql_raw,
        const float* __restrict__ tsteps,
        const float* __restrict__ W1, const float* __restrict__ b1,
        const float* __restrict__ sW1, const float* __restrict__ sb1,
        float* __restrict__ h_ws, float* __restrict__ sh_ws) {
    __shared__ float lds[DD];   // 16 KB; sigma branch uses first 128 floats
    const int tid = threadIdx.x;

    if (blockIdx.x < BB) {
        const int b = blockIdx.x;
        const bool is64 = seql_is64(seql_raw);
        const float denom = fmaxf((float)load_seqlen(seql_raw, b, is64), 1.0f);
        const float inv = 1.0f / denom;
        // reduce partials -> pooled (in LDS)
#pragma unroll
        for (int i = 0; i < 4; ++i) {
            int d0 = (i * 256 + tid) * 4;
            float4 s = make_float4(0.f, 0.f, 0.f, 0.f);
#pragma unroll
            for (int sy = 0; sy < SCHUNKS; ++sy) {
                float4 p = *(const float4*)(partial + ((size_t)sy * BB + b) * DD + d0);
                s.x += p.x; s.y += p.y; s.z += p.z; s.w += p.w;
            }
            lds[d0 + 0] = s.x * inv; lds[d0 + 1] = s.y * inv;
            lds[d0 + 2] = s.z * inv; lds[d0 + 3] = s.w * inv;
        }
        __syncthreads();
        float acc = b1[tid];
#pragma unroll 8
        for (int k = 0; k < DD; ++k)
            acc = fmaf(lds[k], W1[(size_t)k * COND_H + tid], acc);
        // exact GELU: 0.5*x*(1+erf(x/sqrt(2)))
        float g = 0.5f * acc * (1.0f + erff(acc * 0.70710678118654752f));
        h_ws[b * COND_H + tid] = g;
    } else {
        const int b = blockIdx.x - BB;
        if (tid < SIG_F / 2) {
            float t = tsteps[b];
            float fr = expf(-9.210340371976184f * (float)tid * (1.0f / 64.0f));
            float ang = t * fr;
            lds[tid]      = cosf(ang);
            lds[tid + 64] = sinf(ang);
        }
        __syncthreads();
        float acc = sb1[tid];
#pragma unroll 8
        for (int c = 0; c < SIG_F; ++c)
            acc = fmaf(lds[c], sW1[c * SIG_H + tid], acc);
        // SiLU
        float s = acc / (1.0f + expf(-acc));
        sh_ws[b * SIG_H + tid] = s;
    }
}

// ---------------------------------------------------------------
// Kernel 3: postfix = h @ W2 + b2 + sh @ sW2 + sb2, spliced into out.
// 256 blocks x 256 threads. Thread layout: tj = tid&31 (handles 4 cols each,
// 128 cols/block), bg = tid>>5 (handles 8 of the 64 batch rows).
// h (all 64 rows) staged in 64 KB LDS; two passes (W2 then sW2) reuse LDS.
// ---------------------------------------------------------------
__global__ __launch_bounds__(256) void k_layer2_splice(
        const float* __restrict__ h_ws, const float* __restrict__ sh_ws,
        const float* __restrict__ W2, const float* __restrict__ b2,
        const float* __restrict__ sW2, const float* __restrict__ sb2,
        const int* __restrict__ seql_raw, float* __restrict__ out) {
    __shared__ float hl[BB * COND_H];  // 16384 floats = 64 KB
    const int tid = threadIdx.x;
    const int tj  = tid & 31;
    const int bg  = tid >> 5;
    const int j   = blockIdx.x * 128 + tj * 4;

    float acc[8][4];
#pragma unroll
    for (int i = 0; i < 8; ++i)
#pragma unroll
        for (int q = 0; q < 4; ++q) acc[i][q] = 0.0f;

    for (int pass = 0; pass < 2; ++pass) {
        const float* Hs = pass ? sh_ws : h_ws;
        const float* Wm = pass ? sW2 : W2;
        __syncthreads();
#pragma unroll
        for (int i = 0; i < 16; ++i) {
            int idx = (i * 256 + tid) * 4;
            *(float4*)&hl[idx] = *(const float4*)&Hs[idx];
        }
        __syncthreads();

        for (int c4 = 0; c4 < COND_H / 4; ++c4) {
            float wf[4][4];
#pragma unroll
            for (int cc = 0; cc < 4; ++cc) {
                float4 w = *(const float4*)&Wm[(size_t)(c4 * 4 + cc) * KD + j];
                wf[cc][0] = w.x; wf[cc][1] = w.y; wf[cc][2] = w.z; wf[cc][3] = w.w;
            }
#pragma unroll
            for (int b8 = 0; b8 < 8; ++b8) {
                const float4 hv = *(const float4*)&hl[(bg * 8 + b8) * COND_H + c4 * 4];
#pragma unroll
                for (int jj = 0; jj < 4; ++jj) {
                    float a = acc[b8][jj];
                    a = fmaf(hv.x, wf[0][jj], a);
                    a = fmaf(hv.y, wf[1][jj], a);
                    a = fmaf(hv.z, wf[2][jj], a);
                    a = fmaf(hv.w, wf[3][jj], a);
                    acc[b8][jj] = a;
                }
            }
        }
    }

    // epilogue: bias + splice write
    float4 bb = *(const float4*)&b2[j];
    float4 sb = *(const float4*)&sb2[j];
    bb.x += sb.x; bb.y += sb.y; bb.z += sb.z; bb.w += sb.w;

    const int k = j >> 12;      // j / D
    const int d = j & (DD - 1); // j % D
    const bool is64 = seql_is64(seql_raw);
#pragma unroll
    for (int b8 = 0; b8 < 8; ++b8) {
        const int b = bg * 8 + b8;
        const int sl = load_seqlen(seql_raw, b, is64);
        size_t o = ((size_t)b * SS + (size_t)(sl + k)) * DD + d;
        float4 v;
        v.x = acc[b8][0] + bb.x;
        v.y = acc[b8][1] + bb.y;
        v.z = acc[b8][2] + bb.z;
        v.w = acc[b8][3] + bb.w;
        *(float4*)&out[o] = v;
    }
}

extern "C" void kernel_launch(void* const* d_in, const int* in_sizes, int n_in,
                              void* d_out, int out_size, void* d_ws, size_t ws_size,
                              hipStream_t stream) {
    const float* emb    = (const float*)d_in[0];
    const int*   seql   = (const int*)  d_in[1];   // int32 or int64 (detected on device)
    const float* tsteps = (const float*)d_in[2];
    const float* W1     = (const float*)d_in[3];
    const float* b1     = (const float*)d_in[4];
    const float* W2     = (const float*)d_in[5];
    const float* b2     = (const float*)d_in[6];
    const float* sW1    = (const float*)d_in[7];
    const float* sb1    = (const float*)d_in[8];
    const float* sW2    = (const float*)d_in[9];
    const float* sb2    = (const float*)d_in[10];
    float* out = (float*)d_out;

    const size_t PART_FLOATS = (size_t)SCHUNKS * BB * DD;  // 2,097,152
    float* partial = (float*)d_ws;
    float* h_ws    = partial + PART_FLOATS;
    float* sh_ws   = h_ws + (size_t)BB * COND_H;

    hipLaunchKernelGGL(k_copy_pool, dim3(4, 8, 64), dim3(256), 0, stream,
                       emb, seql, out, partial);
    hipLaunchKernelGGL(k_layer1, dim3(128), dim3(256), 0, stream,
                       partial, seql, tsteps, W1, b1, sW1, sb1, h_ws, sh_ws);
    hipLaunchKernelGGL(k_layer2_splice, dim3(256), dim3(256), 0, stream,
                       h_ws, sh_ws, W2, b2, sW2, sb2, seql, out);
}

// Round 2
// 272.337 us; speedup vs baseline: 1.8743x; 1.8743x over previous
//
#include <hip/hip_runtime.h>
#include <math.h>

#define BB 64
#define SS 512
#define DD 4096
#define KK 8
#define COND_H 256
#define SIG_F 128
#define SIG_H 256
#define KD (KK*DD)        // 32768
#define SCHUNKS 8
#define SROWS (SS/SCHUNKS) // 64
#define KSLICES 32
#define KSL (DD/KSLICES)   // 128

// ---- seqlens dtype detection (int64 vs int32) ----
__device__ inline bool seql_is64(const int* sq) {
    bool is64 = true;
#pragma unroll
    for (int i = 1; i < 64; i += 2) is64 &= (sq[i] == 0);
    return is64;
}
__device__ inline int load_seqlen(const int* sq, int b, bool is64) {
    return is64 ? sq[2 * b] : sq[b];
}

// ---------------------------------------------------------------
// Kernel 1: copy emb -> out, accumulate masked partial sums for pooling.
// grid (4 dchunks, 8 schunks, 64 b), 256 threads, float4 per thread.
// partial layout: [SCHUNKS][B][D]
// ---------------------------------------------------------------
__global__ __launch_bounds__(256) void k_copy_pool(
        const float* __restrict__ emb, const int* __restrict__ seql_raw,
        float* __restrict__ out, float* __restrict__ partial) {
    const int dchunk = blockIdx.x;   // 0..3
    const int sy     = blockIdx.y;   // 0..7
    const int b      = blockIdx.z;   // 0..63
    const int tid    = threadIdx.x;
    const int d0     = dchunk * 1024 + tid * 4;

    const bool is64 = seql_is64(seql_raw);
    const int  sl   = load_seqlen(seql_raw, b, is64);

    size_t base = ((size_t)b * SS + (size_t)sy * SROWS) * DD + d0;
    float4 sum = make_float4(0.f, 0.f, 0.f, 0.f);

    const int s0 = sy * SROWS;
#pragma unroll 4
    for (int i = 0; i < SROWS; ++i) {
        float4 v = *(const float4*)(emb + base);
        *(float4*)(out + base) = v;
        if (s0 + i < sl) {
            sum.x += v.x; sum.y += v.y; sum.z += v.z; sum.w += v.w;
        }
        base += DD;
    }
    size_t pidx = ((size_t)sy * BB + b) * DD + d0;
    *(float4*)(partial + pidx) = sum;
}

// ---------------------------------------------------------------
// Kernel 2a: cond MLP layer-1, K-split GEMM.
// grid (KSLICES=32, BGROUPS=8) = 256 blocks, 256 threads.
// Block (ks, bg): reduce pooled slice [8 b][128 d] from partial into LDS,
// then each thread owns output col t, 8 independent acc chains over 128 k.
// Writes partial_h[ks][b][t]  ([32][64][256]).
// ---------------------------------------------------------------
__global__ __launch_bounds__(256) void k_cond_l1(
        const float* __restrict__ partial, const int* __restrict__ seql_raw,
        const float* __restrict__ W1, float* __restrict__ ph) {
    __shared__ float pooled[8][KSL];   // 4 KB
    const int ks  = blockIdx.x;   // 0..31
    const int bg  = blockIdx.y;   // 0..7
    const int tid = threadIdx.x;

    const bool is64 = seql_is64(seql_raw);

    // step 1: reduce partial over sy, scale by 1/denom -> pooled slice
#pragma unroll
    for (int e = 0; e < 4; ++e) {
        int idx = e * 256 + tid;           // 0..1023
        int b8  = idx >> 7;                // 0..7
        int d   = idx & (KSL - 1);         // 0..127
        int b   = bg * 8 + b8;
        float s = 0.f;
        size_t col = (size_t)ks * KSL + d;
#pragma unroll
        for (int sy = 0; sy < SCHUNKS; ++sy)
            s += partial[((size_t)sy * BB + b) * DD + col];
        float denom = fmaxf((float)load_seqlen(seql_raw, b, is64), 1.0f);
        pooled[b8][d] = s / denom;
    }
    __syncthreads();

    // step 2: dot over 128 k for output col t = tid
    float acc[8];
#pragma unroll
    for (int i = 0; i < 8; ++i) acc[i] = 0.f;
#pragma unroll 8
    for (int k = 0; k < KSL; ++k) {
        float w = W1[((size_t)ks * KSL + k) * COND_H + tid];
#pragma unroll
        for (int b8 = 0; b8 < 8; ++b8)
            acc[b8] = fmaf(pooled[b8][k], w, acc[b8]);
    }
#pragma unroll
    for (int b8 = 0; b8 < 8; ++b8)
        ph[((size_t)ks * BB + bg * 8 + b8) * COND_H + tid] = acc[b8];
}

// ---------------------------------------------------------------
// Kernel 2b: blocks 0..63: reduce partial_h over 32 kslices + bias + GELU -> h
//            blocks 64..127: sigma features + sW1 + SiLU -> sh
// ---------------------------------------------------------------
__global__ __launch_bounds__(256) void k_l1_finish(
        const float* __restrict__ ph, const float* __restrict__ b1,
        const float* __restrict__ tsteps,
        const float* __restrict__ sW1, const float* __restrict__ sb1,
        float* __restrict__ h_ws, float* __restrict__ sh_ws) {
    __shared__ float lds[SIG_F];
    const int tid = threadIdx.x;

    if (blockIdx.x < BB) {
        const int b = blockIdx.x;
        float acc = b1[tid];
#pragma unroll 8
        for (int ks = 0; ks < KSLICES; ++ks)
            acc += ph[((size_t)ks * BB + b) * COND_H + tid];
        float g = 0.5f * acc * (1.0f + erff(acc * 0.70710678118654752f));
        h_ws[b * COND_H + tid] = g;
    } else {
        const int b = blockIdx.x - BB;
        if (tid < SIG_F / 2) {
            float t = tsteps[b];
            float fr = expf(-9.210340371976184f * (float)tid * (1.0f / 64.0f));
            float ang = t * fr;
            lds[tid]      = cosf(ang);
            lds[tid + 64] = sinf(ang);
        }
        __syncthreads();
        float acc = sb1[tid];
#pragma unroll 8
        for (int c = 0; c < SIG_F; ++c)
            acc = fmaf(lds[c], sW1[c * SIG_H + tid], acc);
        float s = acc / (1.0f + expf(-acc));
        sh_ws[b * SIG_H + tid] = s;
    }
}

// ---------------------------------------------------------------
// Kernel 3: postfix = h @ W2 + b2 + sh @ sW2 + sb2, spliced into out.
// 512 blocks x 256 threads, 64 cols/block. tj = tid&15 (4 cols each),
// bg = tid>>4 (4 of the 64 batch rows each). acc[4][4].
// h (all 64 rows) staged in 64 KB LDS; two passes (W2 then sW2) reuse LDS.
// LDS 64KB -> 2 blocks/CU, 512 blocks = all resident.
// ---------------------------------------------------------------
__global__ __launch_bounds__(256) void k_layer2_splice(
        const float* __restrict__ h_ws, const float* __restrict__ sh_ws,
        const float* __restrict__ W2, const float* __restrict__ b2,
        const float* __restrict__ sW2, const float* __restrict__ sb2,
        const int* __restrict__ seql_raw, float* __restrict__ out) {
    __shared__ float hl[BB * COND_H];  // 16384 floats = 64 KB
    const int tid = threadIdx.x;
    const int tj  = tid & 15;
    const int bg  = tid >> 4;
    const int j   = blockIdx.x * 64 + tj * 4;

    float acc[4][4];
#pragma unroll
    for (int i = 0; i < 4; ++i)
#pragma unroll
        for (int q = 0; q < 4; ++q) acc[i][q] = 0.0f;

    for (int pass = 0; pass < 2; ++pass) {
        const float* Hs = pass ? sh_ws : h_ws;
        const float* Wm = pass ? sW2 : W2;
        __syncthreads();
#pragma unroll
        for (int i = 0; i < 16; ++i) {
            int idx = (i * 256 + tid) * 4;
            *(float4*)&hl[idx] = *(const float4*)&Hs[idx];
        }
        __syncthreads();

        for (int c4 = 0; c4 < COND_H / 4; ++c4) {
            float wf[4][4];
#pragma unroll
            for (int cc = 0; cc < 4; ++cc) {
                float4 w = *(const float4*)&Wm[(size_t)(c4 * 4 + cc) * KD + j];
                wf[cc][0] = w.x; wf[cc][1] = w.y; wf[cc][2] = w.z; wf[cc][3] = w.w;
            }
#pragma unroll
            for (int b4 = 0; b4 < 4; ++b4) {
                const float4 hv = *(const float4*)&hl[(bg * 4 + b4) * COND_H + c4 * 4];
#pragma unroll
                for (int jj = 0; jj < 4; ++jj) {
                    float a = acc[b4][jj];
                    a = fmaf(hv.x, wf[0][jj], a);
                    a = fmaf(hv.y, wf[1][jj], a);
                    a = fmaf(hv.z, wf[2][jj], a);
                    a = fmaf(hv.w, wf[3][jj], a);
                    acc[b4][jj] = a;
                }
            }
        }
    }

    // epilogue: bias + splice write
    float4 bb = *(const float4*)&b2[j];
    float4 sb = *(const float4*)&sb2[j];
    bb.x += sb.x; bb.y += sb.y; bb.z += sb.z; bb.w += sb.w;

    const int k = j >> 12;      // j / D
    const int d = j & (DD - 1); // j % D
    const bool is64 = seql_is64(seql_raw);
#pragma unroll
    for (int b4 = 0; b4 < 4; ++b4) {
        const int b = bg * 4 + b4;
        const int sl = load_seqlen(seql_raw, b, is64);
        size_t o = ((size_t)b * SS + (size_t)(sl + k)) * DD + d;
        float4 v;
        v.x = acc[b4][0] + bb.x;
        v.y = acc[b4][1] + bb.y;
        v.z = acc[b4][2] + bb.z;
        v.w = acc[b4][3] + bb.w;
        *(float4*)&out[o] = v;
    }
}

extern "C" void kernel_launch(void* const* d_in, const int* in_sizes, int n_in,
                              void* d_out, int out_size, void* d_ws, size_t ws_size,
                              hipStream_t stream) {
    const float* emb    = (const float*)d_in[0];
    const int*   seql   = (const int*)  d_in[1];   // int32 or int64 (detected on device)
    const float* tsteps = (const float*)d_in[2];
    const float* W1     = (const float*)d_in[3];
    const float* b1     = (const float*)d_in[4];
    const float* W2     = (const float*)d_in[5];
    const float* b2     = (const float*)d_in[6];
    const float* sW1    = (const float*)d_in[7];
    const float* sb1    = (const float*)d_in[8];
    const float* sW2    = (const float*)d_in[9];
    const float* sb2    = (const float*)d_in[10];
    float* out = (float*)d_out;

    const size_t PART_FLOATS = (size_t)SCHUNKS * BB * DD;   // 2,097,152 (8 MB)
    const size_t PH_FLOATS   = (size_t)KSLICES * BB * COND_H; // 524,288 (2 MB)
    float* partial = (float*)d_ws;
    float* ph      = partial + PART_FLOATS;
    float* h_ws    = ph + PH_FLOATS;
    float* sh_ws   = h_ws + (size_t)BB * COND_H;

    hipLaunchKernelGGL(k_copy_pool, dim3(4, 8, 64), dim3(256), 0, stream,
                       emb, seql, out, partial);
    hipLaunchKernelGGL(k_cond_l1, dim3(KSLICES, 8), dim3(256), 0, stream,
                       partial, seql, W1, ph);
    hipLaunchKernelGGL(k_l1_finish, dim3(128), dim3(256), 0, stream,
                       ph, b1, tsteps, sW1, sb1, h_ws, sh_ws);
    hipLaunchKernelGGL(k_layer2_splice, dim3(512), dim3(256), 0, stream,
                       h_ws, sh_ws, W2, b2, sW2, sb2, seql, out);
}

// Round 4
// 263.134 us; speedup vs baseline: 1.9399x; 1.0350x over previous
//
#include <hip/hip_runtime.h>
#include <math.h>

#define BB 64
#define SS 512
#define DD 4096
#define KK 8
#define COND_H 256
#define SIG_F 128
#define SIG_H 256
#define KD (KK*DD)         // 32768
#define SCHUNKS 8
#define SROWS (SS/SCHUNKS) // 64
#define KSLICES 64
#define KSL (DD/KSLICES)   // 64
#define PADC 260           // 256 + 4 pad: row bank-shift of 4, float4-aligned

typedef float f32x4 __attribute__((ext_vector_type(4)));
__device__ inline f32x4 nt_load4(const float* p) {
    return __builtin_nontemporal_load((const f32x4*)p);
}
__device__ inline void nt_store4(float* p, f32x4 v) {
    __builtin_nontemporal_store(v, (f32x4*)p);
}

// ---- seqlens dtype detection (int64 vs int32) ----
__device__ inline bool seql_is64(const int* sq) {
    bool is64 = true;
#pragma unroll
    for (int i = 1; i < 64; i += 2) is64 &= (sq[i] == 0);
    return is64;
}
__device__ inline int load_seqlen(const int* sq, int b, bool is64) {
    return is64 ? sq[2 * b] : sq[b];
}

// ---------------------------------------------------------------
// Kernel 1: copy emb -> out (nontemporal), masked partial sums for pooling.
// grid (4 dchunks, 8 schunks, 64 b), 256 threads, float4 per thread.
// partial layout: [SCHUNKS][B][D]
// ---------------------------------------------------------------
__global__ __launch_bounds__(256) void k_copy_pool(
        const float* __restrict__ emb, const int* __restrict__ seql_raw,
        float* __restrict__ out, float* __restrict__ partial) {
    const int dchunk = blockIdx.x;   // 0..3
    const int sy     = blockIdx.y;   // 0..7
    const int b      = blockIdx.z;   // 0..63
    const int tid    = threadIdx.x;
    const int d0     = dchunk * 1024 + tid * 4;

    const bool is64 = seql_is64(seql_raw);
    const int  sl   = load_seqlen(seql_raw, b, is64);

    size_t base = ((size_t)b * SS + (size_t)sy * SROWS) * DD + d0;
    f32x4 sum = {0.f, 0.f, 0.f, 0.f};

    const int s0 = sy * SROWS;
#pragma unroll 4
    for (int i = 0; i < SROWS; ++i) {
        f32x4 v = nt_load4(emb + base);
        nt_store4(out + base, v);
        if (s0 + i < sl) sum += v;
        base += DD;
    }
    size_t pidx = ((size_t)sy * BB + b) * DD + d0;
    *(f32x4*)(partial + pidx) = sum;
}

// ---------------------------------------------------------------
// Kernel 2a: blocks 0..511: cond layer-1 K-split GEMM (ks=bx>>3, bg=bx&7).
//            blocks 512..519: sigma features + sW1 + SiLU -> sh_ws.
// cond: reduce pooled slice [8 b][64 d] into LDS, then each thread owns
// output col t with 8 independent acc chains over 64 k.
// ph layout: [KSLICES][B][COND_H]
// ---------------------------------------------------------------
__global__ __launch_bounds__(256) void k_l1_split(
        const float* __restrict__ partial, const int* __restrict__ seql_raw,
        const float* __restrict__ W1, const float* __restrict__ tsteps,
        const float* __restrict__ sW1, const float* __restrict__ sb1,
        float* __restrict__ ph, float* __restrict__ sh_ws) {
    __shared__ float smem[8][SIG_F];   // cond uses [8][64], sigma uses [8][128]
    const int tid = threadIdx.x;

    if (blockIdx.x < 512) {
        const int ks = blockIdx.x >> 3;   // 0..63
        const int bg = blockIdx.x & 7;    // 0..7
        const bool is64 = seql_is64(seql_raw);

        // reduce partial over sy, scale by 1/denom -> pooled slice in LDS
#pragma unroll
        for (int e = 0; e < 2; ++e) {
            int idx = e * 256 + tid;           // 0..511
            int b8  = idx >> 6;                // 0..7
            int d   = idx & (KSL - 1);         // 0..63
            int b   = bg * 8 + b8;
            float s = 0.f;
            size_t col = (size_t)ks * KSL + d;
#pragma unroll
            for (int sy = 0; sy < SCHUNKS; ++sy)
                s += partial[((size_t)sy * BB + b) * DD + col];
            float denom = fmaxf((float)load_seqlen(seql_raw, b, is64), 1.0f);
            smem[b8][d] = s / denom;
        }
        __syncthreads();

        float acc[8];
#pragma unroll
        for (int i = 0; i < 8; ++i) acc[i] = 0.f;
#pragma unroll 8
        for (int k = 0; k < KSL; ++k) {
            float w = W1[((size_t)ks * KSL + k) * COND_H + tid];
#pragma unroll
            for (int b8 = 0; b8 < 8; ++b8)
                acc[b8] = fmaf(smem[b8][k], w, acc[b8]);
        }
#pragma unroll
        for (int b8 = 0; b8 < 8; ++b8)
            ph[((size_t)ks * BB + bg * 8 + b8) * COND_H + tid] = acc[b8];
    } else {
        const int sb = blockIdx.x - 512;   // 0..7, handles b = sb*8 .. +7
        // features: 8 b x 128 f -> LDS
#pragma unroll
        for (int e = 0; e < 4; ++e) {
            int idx = e * 256 + tid;       // 0..1023
            int b8  = idx >> 7;            // 0..7
            int f   = idx & 127;           // 0..127
            float t = tsteps[sb * 8 + b8];
            int fi = (f < 64) ? f : (f - 64);
            float fr = expf(-0.14391156831213413f * (float)fi);
            float ang = t * fr;
            smem[b8][f] = (f < 64) ? cosf(ang) : sinf(ang);
        }
        __syncthreads();

        float acc[8];
#pragma unroll
        for (int i = 0; i < 8; ++i) acc[i] = sb1[tid];
#pragma unroll 8
        for (int c = 0; c < SIG_F; ++c) {
            float w = sW1[c * SIG_H + tid];
#pragma unroll
            for (int b8 = 0; b8 < 8; ++b8)
                acc[b8] = fmaf(smem[b8][c], w, acc[b8]);
        }
#pragma unroll
        for (int b8 = 0; b8 < 8; ++b8) {
            float a = acc[b8];
            float s = a / (1.0f + expf(-a));
            sh_ws[(sb * 8 + b8) * SIG_H + tid] = s;
        }
    }
}

// ---------------------------------------------------------------
// Kernel 2b: reduce ph over 64 kslices + bias + exact GELU -> h_ws. 64 blocks.
// ---------------------------------------------------------------
__global__ __launch_bounds__(256) void k_l1_finish(
        const float* __restrict__ ph, const float* __restrict__ b1,
        float* __restrict__ h_ws) {
    const int b = blockIdx.x;
    const int tid = threadIdx.x;
    float acc = b1[tid];
#pragma unroll 8
    for (int ks = 0; ks < KSLICES; ++ks)
        acc += ph[((size_t)ks * BB + b) * COND_H + tid];
    float g = 0.5f * acc * (1.0f + erff(acc * 0.70710678118654752f));
    h_ws[b * COND_H + tid] = g;
}

// ---------------------------------------------------------------
// Kernel 3: postfix = h @ W2 + sh @ sW2 + (b2+sb2), spliced into out.
// 512 blocks x 256 threads, 64 cols/block. tj = tid&15 (4 cols each),
// bg = tid>>4 (4 of the 64 batch rows each). acc[4][4] accumulates BOTH
// GEMMs (h and sh staged together, 133 KB LDS, padded rows).
// ---------------------------------------------------------------
__global__ __launch_bounds__(256) void k_layer2_splice(
        const float* __restrict__ h_ws, const float* __restrict__ sh_ws,
        const float* __restrict__ W2, const float* __restrict__ b2,
        const float* __restrict__ sW2, const float* __restrict__ sb2,
        const int* __restrict__ seql_raw, float* __restrict__ out) {
    __shared__ float hl[BB][PADC];   // 66.6 KB
    __shared__ float sl_[BB][PADC];  // 66.6 KB  (total 133 KB < 160 KB)
    const int tid = threadIdx.x;
    const int tj  = tid & 15;
    const int bg  = tid >> 4;
    const int j   = blockIdx.x * 64 + tj * 4;

    // stage h and sh: 4096 float4 each (64 rows x 64 float4), 16 per thread
#pragma unroll
    for (int e = 0; e < 16; ++e) {
        int idx = e * 256 + tid;    // 0..4095
        int row = idx >> 6;         // 0..63
        int c4i = idx & 63;         // 0..63
        *(float4*)&hl[row][c4i * 4]  = *(const float4*)&h_ws[row * COND_H + c4i * 4];
        *(float4*)&sl_[row][c4i * 4] = *(const float4*)&sh_ws[row * COND_H + c4i * 4];
    }
    __syncthreads();

    float acc[4][4];
#pragma unroll
    for (int i = 0; i < 4; ++i)
#pragma unroll
        for (int q = 0; q < 4; ++q) acc[i][q] = 0.0f;

    for (int pass = 0; pass < 2; ++pass) {
        const float* __restrict__ Wm = pass ? sW2 : W2;
        const float (*A)[PADC] = pass ? sl_ : hl;
#pragma unroll 2
        for (int c4 = 0; c4 < COND_H / 4; ++c4) {
            float wf[4][4];
#pragma unroll
            for (int cc = 0; cc < 4; ++cc) {
                float4 w = *(const float4*)&Wm[(size_t)(c4 * 4 + cc) * KD + j];
                wf[cc][0] = w.x; wf[cc][1] = w.y; wf[cc][2] = w.z; wf[cc][3] = w.w;
            }
#pragma unroll
            for (int b4 = 0; b4 < 4; ++b4) {
                const float4 av = *(const float4*)&A[bg * 4 + b4][c4 * 4];
#pragma unroll
                for (int jj = 0; jj < 4; ++jj) {
                    float a = acc[b4][jj];
                    a = fmaf(av.x, wf[0][jj], a);
                    a = fmaf(av.y, wf[1][jj], a);
                    a = fmaf(av.z, wf[2][jj], a);
                    a = fmaf(av.w, wf[3][jj], a);
                    acc[b4][jj] = a;
                }
            }
        }
    }

    // epilogue: bias + splice write
    float4 bb = *(const float4*)&b2[j];
    float4 sb = *(const float4*)&sb2[j];
    bb.x += sb.x; bb.y += sb.y; bb.z += sb.z; bb.w += sb.w;

    const int k = j >> 12;      // j / D
    const int d = j & (DD - 1); // j % D
    const bool is64 = seql_is64(seql_raw);
#pragma unroll
    for (int b4 = 0; b4 < 4; ++b4) {
        const int b = bg * 4 + b4;
        const int sl = load_seqlen(seql_raw, b, is64);
        size_t o = ((size_t)b * SS + (size_t)(sl + k)) * DD + d;
        float4 v;
        v.x = acc[b4][0] + bb.x;
        v.y = acc[b4][1] + bb.y;
        v.z = acc[b4][2] + bb.z;
        v.w = acc[b4][3] + bb.w;
        *(float4*)&out[o] = v;
    }
}

extern "C" void kernel_launch(void* const* d_in, const int* in_sizes, int n_in,
                              void* d_out, int out_size, void* d_ws, size_t ws_size,
                              hipStream_t stream) {
    const float* emb    = (const float*)d_in[0];
    const int*   seql   = (const int*)  d_in[1];   // int32 or int64 (detected on device)
    const float* tsteps = (const float*)d_in[2];
    const float* W1     = (const float*)d_in[3];
    const float* b1     = (const float*)d_in[4];
    const float* W2     = (const float*)d_in[5];
    const float* b2     = (const float*)d_in[6];
    const float* sW1    = (const float*)d_in[7];
    const float* sb1    = (const float*)d_in[8];
    const float* sW2    = (const float*)d_in[9];
    const float* sb2    = (const float*)d_in[10];
    float* out = (float*)d_out;

    const size_t PART_FLOATS = (size_t)SCHUNKS * BB * DD;     // 8 MB
    const size_t PH_FLOATS   = (size_t)KSLICES * BB * COND_H; // 4 MB
    float* partial = (float*)d_ws;
    float* ph      = partial + PART_FLOATS;
    float* h_ws    = ph + PH_FLOATS;
    float* sh_ws   = h_ws + (size_t)BB * COND_H;

    hipLaunchKernelGGL(k_copy_pool, dim3(4, 8, 64), dim3(256), 0, stream,
                       emb, seql, out, partial);
    hipLaunchKernelGGL(k_l1_split, dim3(520), dim3(256), 0, stream,
                       partial, seql, W1, tsteps, sW1, sb1, ph, sh_ws);
    hipLaunchKernelGGL(k_l1_finish, dim3(64), dim3(256), 0, stream,
                       ph, b1, h_ws);
    hipLaunchKernelGGL(k_layer2_splice, dim3(512), dim3(256), 0, stream,
                       h_ws, sh_ws, W2, b2, sW2, sb2, seql, out);
}